// Round 15
// baseline (112.602 us; speedup 1.0000x reference)
//
#include <hip/hip_runtime.h>
#include <hip/hip_fp16.h>

// Problem constants: B=8, C=32, H=256, W=448, kernel_size=1
constexpr int B = 8;
constexpr int C = 32;
constexpr int H = 256;
constexpr int W = 448;
constexpr int HW = H * W;

// Output-centric tiling; one thread per output cell. A source is "handled"
// iff floor(p+flow)-p is in [-RAD, RAD-1] on both dims; unhandled in-image
// sources go to a compact outlier list in d_ws (processed by a 2nd kernel).
// R15 = R14 retiled 32x8 -> 64x8 (NT=512): doubles the HBM granule
// (row-run per channel: 128 B -> 256 B stores, 288 B staged reads) to test
// the BW-pattern-efficiency theory (R14 moved 181 MB at only 1.8 TB/s with
// all pipes <25% busy).
constexpr int TW  = 64;           // 448/64 = 7 tiles in x
constexpr int TH  = 8;            // 256/8  = 32 tiles in y
constexpr int RAD = 3;
constexpr int WXV = 72;           // value/geometry window stride; gx in [ox-4, ox+68)
constexpr int WY  = TH + 2 * RAD; // 14
constexpr int NV  = WXV * WY;     // 1008
constexpr int NT  = 512;          // == TW*TH, one thread per cell
constexpr int GITER = (NV + NT - 1) / NT;    // 2 geometry iters
constexpr int NG4 = (WXV / 4) * WY;          // 252 float4 col-groups
constexpr int NITEM = NG4 * 8;               // 2016 staging items per pass
constexpr int KITER = (NITEM + NT - 1) / NT; // 4

static __device__ __forceinline__ unsigned pkrtz(float a, float b) {
    return __builtin_bit_cast(unsigned, __builtin_amdgcn_cvt_pkrtz(a, b));
}

static __device__ __forceinline__ __half2 h2(unsigned u) {
    union { unsigned u; __half2 h; } x;
    x.u = u;
    return x.h;
}

__global__ __launch_bounds__(NT)
void splat_out(const float* __restrict__ in1,
               const float* __restrict__ flow,
               float* __restrict__ out,
               unsigned* __restrict__ wcnt,
               unsigned* __restrict__ wlist,
               unsigned cap) {
    // mAllS[cell] bit j=(dy+3)*8+(dx+3): source at window offset (dx,dy)
    //   from the cell contributes; mDxS/mDyS give that entry's corner dxx/dyy.
    // geomW[i] (i = wy*72 + wv): .x = half2(w00,w10), .y = half2(w01,w11).
    // valV[cp*NV + i]: packed-half channel pair (2cp, 2cp+1) of source i
    //   for the current 16-channel pass.
    __shared__ unsigned long long mAllS[NT];  // 4 KB
    __shared__ unsigned long long mDxS[NT];   // 4 KB
    __shared__ unsigned long long mDyS[NT];   // 4 KB
    __shared__ uint2    geomW[NV];            // 8.1 KB
    __shared__ unsigned valV[8 * NV];         // 32.3 KB  (total 52.6 KB)

    int bid = blockIdx.x;
    int b = bid & 7;                 // batch -> XCD affinity
    int t = bid >> 3;                // 0..223
    int ty = t / 7;                  // 0..31
    int tx = t - ty * 7;             // 0..6
    int ox = tx * TW, oy = ty * TH;
    int tid = threadIdx.x;
    int qlx = tid & 63, qly = tid >> 6;
    int qx = ox + qlx, qy = oy + qly;

    mAllS[tid] = 0ull;               // cell index == tid
    mDxS[tid]  = 0ull;
    mDyS[tid]  = 0ull;
    __syncthreads();

    // ---- geometry + 3-mask scatter (once per source) + outlier append ----
    const int fbase = b * 2 * HW;
#pragma unroll
    for (int k = 0; k < GITER; ++k) {
        int i = tid + k * NT;
        if (i < NV) {
            int wy = i / WXV, wv = i - wy * WXV;
            int gx = ox + wv - 4;            // window x-origin is ox-4
            int sy = oy + wy - RAD;
            uint2 wd = make_uint2(0u, 0u);
            if ((unsigned)gx < (unsigned)W && (unsigned)sy < (unsigned)H) {
                int g = sy * W + gx;
                float u = flow[fbase + g];
                float v = flow[fbase + g + HW];
                float txf = (float)gx + u;
                float tyf = (float)sy + v;
                float x0f = floorf(txf), y0f = floorf(tyf);
                int rx = (int)x0f - gx, ry = (int)y0f - sy;
                if (rx >= -RAD && rx <= RAD - 1 && ry >= -RAD && ry <= RAD - 1) {
                    float fx = txf - x0f, fy = tyf - y0f;
                    wd.x = pkrtz((1.f - fx) * (1.f - fy), fx * (1.f - fy));
                    wd.y = pkrtz((1.f - fx) * fy,         fx * fy);
                    // scatter the 4 corners into target cells' masks
#pragma unroll
                    for (int corner = 0; corner < 4; ++corner) {
                        int dxx = corner & 1, dyy = corner >> 1;
                        int ccx = gx + rx + dxx - ox;    // cell tile coords
                        int ccy = sy + ry + dyy - oy;
                        if ((unsigned)ccx < (unsigned)TW &&
                            (unsigned)ccy < (unsigned)TH) {
                            int cell = ccy * TW + ccx;
                            unsigned long long bit =
                                1ull << ((3 - (ry + dyy)) * 8 + (3 - (rx + dxx)));
                            atomicOr(&mAllS[cell], bit);
                            if (dxx) atomicOr(&mDxS[cell], bit);
                            if (dyy) atomicOr(&mDyS[cell], bit);
                        }
                    }
                } else if (wv >= 4 && wv < 4 + TW &&
                           wy >= RAD && wy < RAD + TH) {
                    // unhandled source OWNED by this tile: append exactly once
                    unsigned slot = atomicAdd(wcnt, 1u);
                    if (slot < cap) wlist[slot] = ((unsigned)b << 17) | (unsigned)g;
                }
            }
            geomW[i] = wd;
        }
    }

    const float* inb = in1 + (size_t)b * C * HW;

    // stage 16 channels of pass p: float4-group loads, plane-per-cp layout
    auto stage = [&](int pass) {
#pragma unroll
        for (int k = 0; k < KITER; ++k) {
            int id = tid + k * NT;
            if (id < NITEM) {
                int g4 = id % NG4;           // float4 column group
                int cp = id / NG4;           // channel pair 0..7
                int wy = g4 / (WXV / 4);
                int wv4 = (g4 - wy * (WXV / 4)) * 4;
                int row = min(max(oy + wy - RAD, 0), H - 1);
                int gxb = min(max(ox + wv4 - 4, 0), W - 4);
                // group base is 4-aligned; groups are fully in- or out-of-image,
                // and out-of-image cells are never consumed -> clamp is exact.
                const float* base = inb + (size_t)(16 * pass + 2 * cp) * HW
                                        + (size_t)row * W + gxb;
                float4 a = *reinterpret_cast<const float4*>(base);
                float4 c = *reinterpret_cast<const float4*>(base + (size_t)HW);
                uint4 wv_;
                wv_.x = pkrtz(a.x, c.x);
                wv_.y = pkrtz(a.y, c.y);
                wv_.z = pkrtz(a.z, c.z);
                wv_.w = pkrtz(a.w, c.w);
                *reinterpret_cast<uint4*>(&valV[cp * NV + wy * WXV + wv4]) = wv_;
            }
        }
    };

    stage(0);                        // overlaps the geometry phase
    __syncthreads();

    const unsigned long long m0  = mAllS[tid];
    const unsigned long long mdx = mDxS[tid];
    const unsigned long long mdy = mDyS[tid];
    const int qbase = (qly + RAD) * WXV + (qlx + 4);
    float* outp = out + (size_t)b * C * HW + qy * W + qx;

    // gather 16 channels (8 channel-pair planes); plain coalesced stores
    auto gather = [&](float* o) {
        __half2 acc2[8];
#pragma unroll
        for (int k = 0; k < 8; ++k) acc2[k] = h2(0u);
        unsigned long long m = m0;
        while (m) {
            int j = (int)__builtin_ctzll(m);
            m &= m - 1;
            int wi = qbase + ((j >> 3) - 3) * WXV + ((j & 7) - 3);
            unsigned dxx = (unsigned)(mdx >> j) & 1u;
            unsigned dyy = (unsigned)(mdy >> j) & 1u;
            uint2 wd2 = geomW[wi];
            unsigned wd = dyy ? wd2.y : wd2.x;
            unsigned hq = (wd >> (16u * dxx)) & 0xFFFFu;
            __half2 w2 = h2(hq | (hq << 16));
            acc2[0] = __hfma2(h2(valV[0 * NV + wi]), w2, acc2[0]);
            acc2[1] = __hfma2(h2(valV[1 * NV + wi]), w2, acc2[1]);
            acc2[2] = __hfma2(h2(valV[2 * NV + wi]), w2, acc2[2]);
            acc2[3] = __hfma2(h2(valV[3 * NV + wi]), w2, acc2[3]);
            acc2[4] = __hfma2(h2(valV[4 * NV + wi]), w2, acc2[4]);
            acc2[5] = __hfma2(h2(valV[5 * NV + wi]), w2, acc2[5]);
            acc2[6] = __hfma2(h2(valV[6 * NV + wi]), w2, acc2[6]);
            acc2[7] = __hfma2(h2(valV[7 * NV + wi]), w2, acc2[7]);
        }
#pragma unroll
        for (int k = 0; k < 8; ++k) {
            float2 f = __half22float2(acc2[k]);
            o[(size_t)(2 * k) * HW]     = f.x;
            o[(size_t)(2 * k + 1) * HW] = f.y;
        }
    };

    gather(outp);                    // channels 0..15
    __syncthreads();
    stage(1);
    __syncthreads();
    gather(outp + (size_t)16 * HW);  // channels 16..31
}

// Outlier handling: list mode if the d_ws list didn't overflow, else full
// scan. Runs AFTER splat_out in stream order -> atomicAdds on plain stores.
__global__ void outlier_combined(const float* __restrict__ in1,
                                 const float* __restrict__ flow,
                                 float* __restrict__ out,
                                 const unsigned* __restrict__ wcnt,
                                 const unsigned* __restrict__ wlist,
                                 unsigned cap) {
    unsigned n = *wcnt;
    if (n <= cap) {
        // ---- list mode: 8 threads per entry (4 channels each) ----
        unsigned total = n * 8u;
        for (unsigned idx = blockIdx.x * blockDim.x + threadIdx.x;
             idx < total; idx += gridDim.x * blockDim.x) {
            unsigned e = wlist[idx >> 3];
            int c0 = (int)(idx & 7u) * 4;
            int bb = (int)(e >> 17);
            int p  = (int)(e & 0x1FFFFu);
            int y = p / W, x = p - y * W;

            float u = flow[(bb * 2 + 0) * HW + p];
            float v = flow[(bb * 2 + 1) * HW + p];
            float txf = (float)x + u;
            float tyf = (float)y + v;
            float fx0 = floorf(txf), fy0 = floorf(tyf);
            int x0 = (int)fx0, y0 = (int)fy0;
            float fx = txf - fx0, fy = tyf - fy0;
            float w00 = (1.0f - fx) * (1.0f - fy);
            float w10 = fx * (1.0f - fy);
            float w01 = (1.0f - fx) * fy;
            float w11 = fx * fy;
            bool vx0 = (x0 >= 0) && (x0 < W);
            bool vx1 = (x0 + 1 >= 0) && (x0 + 1 < W);
            bool vy0 = (y0 >= 0) && (y0 < H);
            bool vy1 = (y0 + 1 >= 0) && (y0 + 1 < H);
            long o00 = (long)y0 * W + x0;

            const float* src  = in1 + (size_t)bb * C * HW + (size_t)c0 * HW + p;
            float*       dstb = out + (size_t)bb * C * HW + (size_t)c0 * HW;
            for (int c = 0; c < 4; ++c) {
                float val = src[(size_t)c * HW];
                float* ob = dstb + (size_t)c * HW;
                if (vx0 && vy0) atomicAdd(ob + o00,         w00 * val);
                if (vx1 && vy0) atomicAdd(ob + o00 + 1,     w10 * val);
                if (vx0 && vy1) atomicAdd(ob + o00 + W,     w01 * val);
                if (vx1 && vy1) atomicAdd(ob + o00 + W + 1, w11 * val);
            }
        }
    } else {
        // ---- fallback: deterministic full scan (list overflowed) ----
        int npix = B * HW;
        for (int idx = blockIdx.x * blockDim.x + threadIdx.x;
             idx < npix; idx += gridDim.x * blockDim.x) {
            int b = idx / HW;
            int p = idx - b * HW;
            int y = p / W, x = p - y * W;
            float u = flow[(b * 2 + 0) * HW + p];
            float v = flow[(b * 2 + 1) * HW + p];
            float txf = (float)x + u;
            float tyf = (float)y + v;
            float fx0 = floorf(txf), fy0 = floorf(tyf);
            int x0 = (int)fx0, y0 = (int)fy0;
            int rx = x0 - x, ry = y0 - y;
            bool handled = (rx >= -RAD) && (rx <= RAD - 1) &&
                           (ry >= -RAD) && (ry <= RAD - 1);
            if (handled) continue;
            float fx = txf - fx0, fy = tyf - fy0;
            float w00 = (1.0f - fx) * (1.0f - fy);
            float w10 = fx * (1.0f - fy);
            float w01 = (1.0f - fx) * fy;
            float w11 = fx * fy;
            bool vx0 = (x0 >= 0) && (x0 < W);
            bool vx1 = (x0 + 1 >= 0) && (x0 + 1 < W);
            bool vy0 = (y0 >= 0) && (y0 < H);
            bool vy1 = (y0 + 1 >= 0) && (y0 + 1 < H);
            long o00 = (long)y0 * W + x0;
            const float* src = in1 + (size_t)b * C * HW + p;
            float* dstb = out + (size_t)b * C * HW;
            for (int c = 0; c < C; ++c) {
                float val = src[(size_t)c * HW];
                float* ob = dstb + (size_t)c * HW;
                if (vx0 && vy0) atomicAdd(ob + o00,         w00 * val);
                if (vx1 && vy0) atomicAdd(ob + o00 + 1,     w10 * val);
                if (vx0 && vy1) atomicAdd(ob + o00 + W,     w01 * val);
                if (vx1 && vy1) atomicAdd(ob + o00 + W + 1, w11 * val);
            }
        }
    }
}

extern "C" void kernel_launch(void* const* d_in, const int* in_sizes, int n_in,
                              void* d_out, int out_size, void* d_ws, size_t ws_size,
                              hipStream_t stream) {
    const float* in1  = (const float*)d_in[0];
    const float* flow = (const float*)d_in[1];
    float* out = (float*)d_out;

    unsigned* wcnt  = (unsigned*)d_ws;
    unsigned* wlist = wcnt + 4;   // 16B-aligned list start
    unsigned cap = 0;
    if (ws_size >= 64) {
        size_t c = ws_size / sizeof(unsigned) - 4;
        cap = (c > 0x7FFFFFFFull) ? 0x7FFFFFFFu : (unsigned)c;
    }

    hipMemsetAsync(wcnt, 0, sizeof(unsigned), stream);

    int nblocks = B * (H / TH) * (W / TW);   // 8 * 32 * 7 = 1792
    splat_out<<<nblocks, NT, 0, stream>>>(in1, flow, out, wcnt, wlist, cap);

    outlier_combined<<<256, 256, 0, stream>>>(in1, flow, out, wcnt, wlist, cap);
}

// Round 16
// 108.359 us; speedup vs baseline: 1.0392x; 1.0392x over previous
//
#include <hip/hip_runtime.h>
#include <hip/hip_fp16.h>

// Problem constants: B=8, C=32, H=256, W=448, kernel_size=1
constexpr int B = 8;
constexpr int C = 32;
constexpr int H = 256;
constexpr int W = 448;
constexpr int HW = H * W;

// Output-centric tiling; one thread per output cell. A source is "handled"
// iff floor(p+flow)-p is in [-RAD, RAD-1] on both dims; unhandled in-image
// sources go to a compact outlier list in d_ws (processed by a 2nd kernel).
// R16 targets the LDS pipe (the one un-measured unit; all measured pipes
// <25% across R12-R15):
//  - ONE mask (mAll) instead of three: scatter drops from ~8 to 4 atomicOr
//    per source; gather decodes the corner from geomR8: dxx=6-(j&7)-(g8&7).
//  - ONE pass over all 32 channels: mask walk + weight fetch paid once;
//    barriers 5 -> 3; values read as 8 x ds_read_b64 (uint2 plane-pairs).
//  - LDS 77.6 KB -> 2 blocks/CU (16 waves).
constexpr int TW  = 64;           // 448/64 = 7 tiles in x
constexpr int TH  = 8;            // 256/8  = 32 tiles in y
constexpr int RAD = 3;
constexpr int WXV = 72;           // window stride; gx in [ox-4, ox+68)
constexpr int WY  = TH + 2 * RAD; // 14
constexpr int NV  = WXV * WY;     // 1008
constexpr int NT  = 512;          // == TW*TH, one thread per cell
constexpr int GITER = (NV + NT - 1) / NT;    // 2 geometry iters
constexpr int NG4 = (WXV / 4) * WY;          // 252 float4 col-groups
constexpr int NITEM = NG4 * 8;               // 2016 staging items (8 plane-pairs)
constexpr int KITER = (NITEM + NT - 1) / NT; // 4

static __device__ __forceinline__ unsigned pkrtz(float a, float b) {
    return __builtin_bit_cast(unsigned, __builtin_amdgcn_cvt_pkrtz(a, b));
}

static __device__ __forceinline__ __half2 h2(unsigned u) {
    union { unsigned u; __half2 h; } x;
    x.u = u;
    return x.h;
}

__global__ __launch_bounds__(NT)
void splat_out(const float* __restrict__ in1,
               const float* __restrict__ flow,
               float* __restrict__ out,
               unsigned* __restrict__ wcnt,
               unsigned* __restrict__ wlist,
               unsigned cap) {
    // mAllS[cell] bit j=(dy+3)*8+(dx+3): source at window offset (dx,dy)
    //   from the cell contributes (dx,dy = source - cell).
    // geomR8[i]: (rx+3) | (ry+3)<<3 (0xFF unused-by-gather default).
    // geomW[i]: .x = half2(w00,w10), .y = half2(w01,w11).
    // valV2[pp*NV + i]: uint2 = channels (4pp..4pp+3) of source i, packed
    //   {pkrtz(c0,c1), pkrtz(c2,c3)} -> read with one ds_read_b64.
    __shared__ unsigned long long mAllS[NT];          // 4 KB
    __shared__ unsigned char     geomR8[NV];          // 1 KB
    __shared__ uint2             geomW[NV];           // 8.1 KB
    __shared__ __align__(16) uint2 valV2[8 * NV];     // 64.5 KB (total 77.6 KB)

    int bid = blockIdx.x;
    int b = bid & 7;                 // batch -> XCD affinity
    int t = bid >> 3;                // 0..223
    int ty = t / 7;                  // 0..31
    int tx = t - ty * 7;             // 0..6
    int ox = tx * TW, oy = ty * TH;
    int tid = threadIdx.x;
    int qlx = tid & 63, qly = tid >> 6;
    int qx = ox + qlx, qy = oy + qly;

    mAllS[tid] = 0ull;               // cell index == tid
    __syncthreads();

    // ---- geometry + 1-mask scatter (once per source) + outlier append ----
    const int fbase = b * 2 * HW;
#pragma unroll
    for (int k = 0; k < GITER; ++k) {
        int i = tid + k * NT;
        if (i < NV) {
            int wy = i / WXV, wv = i - wy * WXV;
            int gx = ox + wv - 4;            // window x-origin is ox-4
            int sy = oy + wy - RAD;
            uint2 wd = make_uint2(0u, 0u);
            unsigned gr = 0xFFu;
            if ((unsigned)gx < (unsigned)W && (unsigned)sy < (unsigned)H) {
                int g = sy * W + gx;
                float u = flow[fbase + g];
                float v = flow[fbase + g + HW];
                float txf = (float)gx + u;
                float tyf = (float)sy + v;
                float x0f = floorf(txf), y0f = floorf(tyf);
                int rx = (int)x0f - gx, ry = (int)y0f - sy;
                if (rx >= -RAD && rx <= RAD - 1 && ry >= -RAD && ry <= RAD - 1) {
                    float fx = txf - x0f, fy = tyf - y0f;
                    wd.x = pkrtz((1.f - fx) * (1.f - fy), fx * (1.f - fy));
                    wd.y = pkrtz((1.f - fx) * fy,         fx * fy);
                    gr = (unsigned)(rx + RAD) | ((unsigned)(ry + RAD) << 3);
                    // scatter the 4 corners into target cells' masks
#pragma unroll
                    for (int corner = 0; corner < 4; ++corner) {
                        int dxx = corner & 1, dyy = corner >> 1;
                        int ccx = gx + rx + dxx - ox;    // cell tile coords
                        int ccy = sy + ry + dyy - oy;
                        if ((unsigned)ccx < (unsigned)TW &&
                            (unsigned)ccy < (unsigned)TH) {
                            int cell = ccy * TW + ccx;
                            unsigned long long bit =
                                1ull << ((3 - (ry + dyy)) * 8 + (3 - (rx + dxx)));
                            atomicOr(&mAllS[cell], bit);
                        }
                    }
                } else if (wv >= 4 && wv < 4 + TW &&
                           wy >= RAD && wy < RAD + TH) {
                    // unhandled source OWNED by this tile: append exactly once
                    unsigned slot = atomicAdd(wcnt, 1u);
                    if (slot < cap) wlist[slot] = ((unsigned)b << 17) | (unsigned)g;
                }
            }
            geomR8[i] = (unsigned char)gr;
            geomW[i]  = wd;
        }
    }

    // ---- stage ALL 32 channels: float4-group loads, plane-pair layout ----
    const float* inb = in1 + (size_t)b * C * HW;
#pragma unroll
    for (int k = 0; k < KITER; ++k) {
        int id = tid + k * NT;
        if (id < NITEM) {
            int g4 = id % NG4;               // float4 column group
            int pp = id / NG4;               // plane pair = channels 4pp..4pp+3
            int wy = g4 / (WXV / 4);
            int wv4 = (g4 - wy * (WXV / 4)) * 4;
            int row = min(max(oy + wy - RAD, 0), H - 1);
            int gxb = min(max(ox + wv4 - 4, 0), W - 4);
            // group base is 4-aligned; groups are fully in- or out-of-image,
            // and out-of-image cells are never consumed -> clamp is exact.
            const float* base = inb + (size_t)(4 * pp) * HW
                                    + (size_t)row * W + gxb;
            float4 c0 = *reinterpret_cast<const float4*>(base);
            float4 c1 = *reinterpret_cast<const float4*>(base + (size_t)HW);
            float4 c2 = *reinterpret_cast<const float4*>(base + (size_t)2 * HW);
            float4 c3 = *reinterpret_cast<const float4*>(base + (size_t)3 * HW);
            int vbase = pp * NV + wy * WXV + wv4;    // multiple of 4
            uint4* dst = reinterpret_cast<uint4*>(&valV2[vbase]);
            uint4 w0, w1;
            w0.x = pkrtz(c0.x, c1.x); w0.y = pkrtz(c2.x, c3.x);
            w0.z = pkrtz(c0.y, c1.y); w0.w = pkrtz(c2.y, c3.y);
            w1.x = pkrtz(c0.z, c1.z); w1.y = pkrtz(c2.z, c3.z);
            w1.z = pkrtz(c0.w, c1.w); w1.w = pkrtz(c2.w, c3.w);
            dst[0] = w0;
            dst[1] = w1;
        }
    }
    __syncthreads();

    const unsigned long long m0 = mAllS[tid];
    const int qbase = (qly + RAD) * WXV + (qlx + 4);
    float* outp = out + (size_t)b * C * HW + qy * W + qx;

    // ---- gather: all 32 channels in ONE walk ----
    __half2 acc2[16];
#pragma unroll
    for (int k = 0; k < 16; ++k) acc2[k] = h2(0u);

    unsigned long long m = m0;
    while (m) {
        int j = (int)__builtin_ctzll(m);
        m &= m - 1;
        int wi = qbase + ((j >> 3) - 3) * WXV + ((j & 7) - 3);
        unsigned g8 = geomR8[wi];
        unsigned dxx = 6u - (unsigned)(j & 7) - (g8 & 7u);        // in {0,1}
        unsigned dyy = 6u - (unsigned)(j >> 3) - (g8 >> 3);       // in {0,1}
        uint2 wd2 = geomW[wi];
        unsigned wd = dyy ? wd2.y : wd2.x;
        unsigned hq = (wd >> (16u * dxx)) & 0xFFFFu;
        __half2 w2 = h2(hq | (hq << 16));
#pragma unroll
        for (int pp = 0; pp < 8; ++pp) {
            uint2 vv = valV2[pp * NV + wi];      // ds_read_b64
            acc2[2 * pp + 0] = __hfma2(h2(vv.x), w2, acc2[2 * pp + 0]);
            acc2[2 * pp + 1] = __hfma2(h2(vv.y), w2, acc2[2 * pp + 1]);
        }
    }

    // ---- store: channels (4pp..4pp+3) from acc2[2pp], acc2[2pp+1] ----
    // acc2[2pp].x=c0, .y=c1 ; acc2[2pp+1].x=c2, .y=c3 (pkrtz(a,b) packs a=lo).
#pragma unroll
    for (int pp = 0; pp < 8; ++pp) {
        float2 f01 = __half22float2(acc2[2 * pp + 0]);
        float2 f23 = __half22float2(acc2[2 * pp + 1]);
        outp[(size_t)(4 * pp + 0) * HW] = f01.x;
        outp[(size_t)(4 * pp + 1) * HW] = f01.y;
        outp[(size_t)(4 * pp + 2) * HW] = f23.x;
        outp[(size_t)(4 * pp + 3) * HW] = f23.y;
    }
}

// Outlier handling: list mode if the d_ws list didn't overflow, else full
// scan. Runs AFTER splat_out in stream order -> atomicAdds on plain stores.
__global__ void outlier_combined(const float* __restrict__ in1,
                                 const float* __restrict__ flow,
                                 float* __restrict__ out,
                                 const unsigned* __restrict__ wcnt,
                                 const unsigned* __restrict__ wlist,
                                 unsigned cap) {
    unsigned n = *wcnt;
    if (n <= cap) {
        // ---- list mode: 8 threads per entry (4 channels each) ----
        unsigned total = n * 8u;
        for (unsigned idx = blockIdx.x * blockDim.x + threadIdx.x;
             idx < total; idx += gridDim.x * blockDim.x) {
            unsigned e = wlist[idx >> 3];
            int c0 = (int)(idx & 7u) * 4;
            int bb = (int)(e >> 17);
            int p  = (int)(e & 0x1FFFFu);
            int y = p / W, x = p - y * W;

            float u = flow[(bb * 2 + 0) * HW + p];
            float v = flow[(bb * 2 + 1) * HW + p];
            float txf = (float)x + u;
            float tyf = (float)y + v;
            float fx0 = floorf(txf), fy0 = floorf(tyf);
            int x0 = (int)fx0, y0 = (int)fy0;
            float fx = txf - fx0, fy = tyf - fy0;
            float w00 = (1.0f - fx) * (1.0f - fy);
            float w10 = fx * (1.0f - fy);
            float w01 = (1.0f - fx) * fy;
            float w11 = fx * fy;
            bool vx0 = (x0 >= 0) && (x0 < W);
            bool vx1 = (x0 + 1 >= 0) && (x0 + 1 < W);
            bool vy0 = (y0 >= 0) && (y0 < H);
            bool vy1 = (y0 + 1 >= 0) && (y0 + 1 < H);
            long o00 = (long)y0 * W + x0;

            const float* src  = in1 + (size_t)bb * C * HW + (size_t)c0 * HW + p;
            float*       dstb = out + (size_t)bb * C * HW + (size_t)c0 * HW;
            for (int c = 0; c < 4; ++c) {
                float val = src[(size_t)c * HW];
                float* ob = dstb + (size_t)c * HW;
                if (vx0 && vy0) atomicAdd(ob + o00,         w00 * val);
                if (vx1 && vy0) atomicAdd(ob + o00 + 1,     w10 * val);
                if (vx0 && vy1) atomicAdd(ob + o00 + W,     w01 * val);
                if (vx1 && vy1) atomicAdd(ob + o00 + W + 1, w11 * val);
            }
        }
    } else {
        // ---- fallback: deterministic full scan (list overflowed) ----
        int npix = B * HW;
        for (int idx = blockIdx.x * blockDim.x + threadIdx.x;
             idx < npix; idx += gridDim.x * blockDim.x) {
            int b = idx / HW;
            int p = idx - b * HW;
            int y = p / W, x = p - y * W;
            float u = flow[(b * 2 + 0) * HW + p];
            float v = flow[(b * 2 + 1) * HW + p];
            float txf = (float)x + u;
            float tyf = (float)y + v;
            float fx0 = floorf(txf), fy0 = floorf(tyf);
            int x0 = (int)fx0, y0 = (int)fy0;
            int rx = x0 - x, ry = y0 - y;
            bool handled = (rx >= -RAD) && (rx <= RAD - 1) &&
                           (ry >= -RAD) && (ry <= RAD - 1);
            if (handled) continue;
            float fx = txf - fx0, fy = tyf - fy0;
            float w00 = (1.0f - fx) * (1.0f - fy);
            float w10 = fx * (1.0f - fy);
            float w01 = (1.0f - fx) * fy;
            float w11 = fx * fy;
            bool vx0 = (x0 >= 0) && (x0 < W);
            bool vx1 = (x0 + 1 >= 0) && (x0 + 1 < W);
            bool vy0 = (y0 >= 0) && (y0 < H);
            bool vy1 = (y0 + 1 >= 0) && (y0 + 1 < H);
            long o00 = (long)y0 * W + x0;
            const float* src = in1 + (size_t)b * C * HW + p;
            float* dstb = out + (size_t)b * C * HW;
            for (int c = 0; c < C; ++c) {
                float val = src[(size_t)c * HW];
                float* ob = dstb + (size_t)c * HW;
                if (vx0 && vy0) atomicAdd(ob + o00,         w00 * val);
                if (vx1 && vy0) atomicAdd(ob + o00 + 1,     w10 * val);
                if (vx0 && vy1) atomicAdd(ob + o00 + W,     w01 * val);
                if (vx1 && vy1) atomicAdd(ob + o00 + W + 1, w11 * val);
            }
        }
    }
}

extern "C" void kernel_launch(void* const* d_in, const int* in_sizes, int n_in,
                              void* d_out, int out_size, void* d_ws, size_t ws_size,
                              hipStream_t stream) {
    const float* in1  = (const float*)d_in[0];
    const float* flow = (const float*)d_in[1];
    float* out = (float*)d_out;

    unsigned* wcnt  = (unsigned*)d_ws;
    unsigned* wlist = wcnt + 4;   // 16B-aligned list start
    unsigned cap = 0;
    if (ws_size >= 64) {
        size_t c = ws_size / sizeof(unsigned) - 4;
        cap = (c > 0x7FFFFFFFull) ? 0x7FFFFFFFu : (unsigned)c;
    }

    hipMemsetAsync(wcnt, 0, sizeof(unsigned), stream);

    int nblocks = B * (H / TH) * (W / TW);   // 8 * 32 * 7 = 1792
    splat_out<<<nblocks, NT, 0, stream>>>(in1, flow, out, wcnt, wlist, cap);

    outlier_combined<<<256, 256, 0, stream>>>(in1, flow, out, wcnt, wlist, cap);
}